// Round 13
// baseline (50.808 us; speedup 1.0000x reference)
//
#include <hip/hip_runtime.h>
#include <hip/hip_bf16.h>

#define NHALF 4096
#define TWO_N 8192
#define DDIM 256
#define INV_T 10.0f
// 10 * log2(e): exp(10*s) = exp2(s * SCALE) where s is the raw cosine dot
#define SCALE 14.426950408889634f
// znB fragment-packed layout: byte(kb, row, lk) = kb*KBSTRIDE + row*64 + lk*16
// holding zn[row][kb*32 + lk*8 .. +7] as 16B of bf16.
#define KBSTRIDE ((size_t)TWO_N * 64)

typedef __bf16 v8bf __attribute__((ext_vector_type(8)));
typedef float f32x4 __attribute__((ext_vector_type(4)));

#if __has_builtin(__builtin_amdgcn_exp2f)
#define EXP2F(x) __builtin_amdgcn_exp2f(x)
#else
#define EXP2F(x) exp2f(x)
#endif

static __device__ __forceinline__ unsigned int f2bf(float x) {
    __hip_bfloat16 h = __float2bfloat16(x);
    return (unsigned int)*(unsigned short*)&h;
}

// ---- kernel 1: normalize rows -> fragment-packed bf16 znB; zero rowacc/out --
__global__ __launch_bounds__(256) void ntx_norm_kernel(
    const float* __restrict__ zi, const float* __restrict__ zj,
    char* __restrict__ znB, float* __restrict__ rowacc,
    float* __restrict__ out) {
    const int w = threadIdx.x >> 6;
    const int lane = threadIdx.x & 63;
    const int r = blockIdx.x * 4 + w;
    const float* src = (r < NHALF) ? (zi + (size_t)r * DDIM)
                                   : (zj + (size_t)(r - NHALF) * DDIM);
    float4 v = ((const float4*)src)[lane];
    float ss = v.x * v.x + v.y * v.y + v.z * v.z + v.w * v.w;
#pragma unroll
    for (int m = 1; m < 64; m <<= 1) ss += __shfl_xor(ss, m);
    float rinv = 1.0f / fmaxf(sqrtf(ss), 1e-8f);
    uint2 pk;
    pk.x = f2bf(v.x * rinv) | (f2bf(v.y * rinv) << 16);
    pk.y = f2bf(v.z * rinv) | (f2bf(v.w * rinv) << 16);
    char* dst = znB + (size_t)(lane >> 3) * KBSTRIDE + (size_t)r * 64 +
                ((lane >> 1) & 3) * 16 + (lane & 1) * 8;
    *(uint2*)dst = pk;
    if (blockIdx.x < 32) rowacc[blockIdx.x * 256 + threadIdx.x] = 0.0f;
    if (blockIdx.x == 0 && threadIdx.x == 0) out[0] = 0.0f;
}

// ---- kernel 2: symmetric Gram + exp sums — barrier-free, 1-wave blocks -----
// 2064 blocks x 64 threads (1 wave). Blocks 0..15: the 64 d=64 tiles
// (positive pairs; af reloaded per tile). Blocks 16..2063: task=(rt,g),
// tiles d=4g..4g+3 (ct=(rt-d) mod 128) — every unordered 64x64 tile pair
// exactly once; exactly 4 tiles per task (R12 had 5-tile waves -> 12% tail).
// Per cf step: MFMA batch (setprio-wrapped) -> issue next B loads -> exp/sum
// epilogue of THIS cf (hides the loads; partner wave's MFMAs fill the pipe
// during our epilogue — R12 failure: in-order [all-MFMA then all-epilogue]
// left the matrix pipe idle ~45% with phase-locked waves).
// Single bf[8] + single acc[4]: VGPR ~210 (R12's bfA/bfB ~250, spill risk).
__global__ __launch_bounds__(64, 2) void ntx_gram_kernel(
    const char* __restrict__ znB,
    float* __restrict__ rowacc,    // [TWO_N] atomic accumulation
    float* __restrict__ spos) {    // [TWO_N]
    const int lane = threadIdx.x;
    const int lrow = lane & 15, lk = lane >> 4;

    bool odg[4];
#pragma unroll
    for (int j = 0; j < 4; ++j) odg[j] = (lrow == lk * 4 + j);

    f32x4 af[4][8], bf[8], acc[4];
    float rowsum[4][4];
    int rbase;

#define LOAD_AF()                                                             \
    do {                                                                      \
        _Pragma("unroll")                                                     \
        for (int rf = 0; rf < 4; ++rf) {                                      \
            const char* ab =                                                  \
                znB + (size_t)(rbase + rf * 16 + lrow) * 64 + lk * 16;        \
            _Pragma("unroll")                                                 \
            for (int kb = 0; kb < 8; ++kb)                                    \
                af[rf][kb] = *(const f32x4*)(ab + kb * KBSTRIDE);             \
        }                                                                     \
        _Pragma("unroll")                                                     \
        for (int rf = 0; rf < 4; ++rf)                                        \
            _Pragma("unroll")                                                 \
            for (int kb = 0; kb < 8; ++kb)                                    \
                asm volatile("" : "+v"(af[rf][kb])); /* pin */                \
    } while (0)

#define ZERO_RS()                                                             \
    do {                                                                      \
        _Pragma("unroll")                                                     \
        for (int rf = 0; rf < 4; ++rf)                                        \
            _Pragma("unroll")                                                 \
            for (int j = 0; j < 4; ++j) rowsum[rf][j] = 0.0f;                 \
    } while (0)

#define LOADB(cf)                                                             \
    do {                                                                      \
        _Pragma("unroll")                                                     \
        for (int kb = 0; kb < 8; ++kb)                                        \
            bf[kb] = *(const f32x4*)(zcb + (cf) * 1024 + kb * KBSTRIDE);      \
    } while (0)

#define MFMAB()                                                               \
    do {                                                                      \
        _Pragma("unroll")                                                     \
        for (int rf = 0; rf < 4; ++rf) acc[rf] = (f32x4){0.f, 0.f, 0.f, 0.f}; \
        __builtin_amdgcn_s_setprio(1);                                        \
        _Pragma("unroll")                                                     \
        for (int kb = 0; kb < 8; ++kb) {                                      \
            _Pragma("unroll")                                                 \
            for (int rf = 0; rf < 4; ++rf)                                    \
                acc[rf] = __builtin_amdgcn_mfma_f32_16x16x32_bf16(            \
                    __builtin_bit_cast(v8bf, af[rf][kb]),                     \
                    __builtin_bit_cast(v8bf, bf[kb]), acc[rf], 0, 0, 0);      \
        }                                                                     \
        __builtin_amdgcn_s_setprio(0);                                        \
    } while (0)

#define EPI(cf, SELF, POSB, cbase)                                            \
    do {                                                                      \
        float fce[4];                                                         \
        _Pragma("unroll")                                                     \
        for (int rf = 0; rf < 4; ++rf) {                                      \
            const bool dfrag = (rf == (cf));                                  \
            float p = 0.0f;                                                   \
            _Pragma("unroll")                                                 \
            for (int j = 0; j < 4; ++j) {                                     \
                const float sv = acc[rf][j];                                  \
                const bool od = dfrag && odg[j];                              \
                if ((POSB) && od) {                                           \
                    const int u = rf * 16 + lk * 4 + j;                       \
                    spos[rbase + u] = sv * INV_T;                             \
                    spos[(cbase) + u] = sv * INV_T;                           \
                }                                                             \
                float e = EXP2F(sv * SCALE);                                  \
                e = ((SELF) && od) ? 0.0f : e;                                \
                rowsum[rf][j] += e;                                           \
                p += e;                                                       \
            }                                                                 \
            fce[rf] = p;                                                      \
        }                                                                     \
        if (!(SELF)) {                                                        \
            float ce = (fce[0] + fce[1]) + (fce[2] + fce[3]);                 \
            ce += __shfl_xor(ce, 16);                                         \
            ce += __shfl_xor(ce, 32);                                         \
            if (lane < 16)                                                    \
                atomicAdd(&rowacc[(cbase) + (cf) * 16 + lrow], ce);           \
        }                                                                     \
    } while (0)

#define DO_TILE(dd, SELF, POSB)                                               \
    do {                                                                      \
        const int ct = (((rbase >> 6) - (dd)) + 128) & 127;                   \
        const int cb = ct * 64;                                               \
        const char* zcb = znB + (size_t)(cb + lrow) * 64 + lk * 16;           \
        LOADB(0);                                                             \
        MFMAB(); LOADB(1); EPI(0, SELF, POSB, cb);                            \
        MFMAB(); LOADB(2); EPI(1, SELF, POSB, cb);                            \
        MFMAB(); LOADB(3); EPI(2, SELF, POSB, cb);                            \
        MFMAB();           EPI(3, SELF, POSB, cb);                            \
    } while (0)

#define FLUSH_RS()                                                            \
    do {                                                                      \
        _Pragma("unroll")                                                     \
        for (int rf = 0; rf < 4; ++rf) {                                      \
            _Pragma("unroll")                                                 \
            for (int j = 0; j < 4; ++j) {                                     \
                float v = rowsum[rf][j];                                      \
                v += __shfl_xor(v, 1);                                        \
                v += __shfl_xor(v, 2);                                        \
                v += __shfl_xor(v, 4);                                        \
                v += __shfl_xor(v, 8);                                        \
                if (lrow == 0)                                                \
                    atomicAdd(&rowacc[rbase + rf * 16 + lk * 4 + j], v);      \
            }                                                                 \
        }                                                                     \
    } while (0)

    if (blockIdx.x < 16) {
        // d=64 tiles: rt = blockIdx*4+s, ct = rt+64; positives, no diag mask.
#pragma unroll 1
        for (int s = 0; s < 4; ++s) {
            rbase = (blockIdx.x * 4 + s) * 64;
            LOAD_AF();
            ZERO_RS();
            DO_TILE(64, false, true);
            FLUSH_RS();
        }
    } else {
        const int t = blockIdx.x - 16;
        const int rt = t >> 4, g = t & 15;
        rbase = rt * 64;
        LOAD_AF();
        ZERO_RS();
#pragma unroll 1
        for (int s = 0; s < 4; ++s) {
            const int d = g * 4 + s;
            const bool self = (d == 0);
            DO_TILE(d, self, false);
        }
        FLUSH_RS();
    }
#undef LOAD_AF
#undef ZERO_RS
#undef LOADB
#undef MFMAB
#undef EPI
#undef DO_TILE
#undef FLUSH_RS
}

// ---------------- kernel 3: finalize ----------------
__global__ __launch_bounds__(256) void ntx_final_kernel(
    const float* __restrict__ rowacc, const float* __restrict__ spos,
    float* __restrict__ out) {
    const int tid = threadIdx.x;
    const int r = blockIdx.x * 256 + tid;
    float nll = logf(rowacc[r]) - spos[r];
    __shared__ float red[256];
    red[tid] = nll;
    __syncthreads();
    for (int s = 128; s > 0; s >>= 1) {
        if (tid < s) red[tid] += red[tid + s];
        __syncthreads();
    }
    if (tid == 0) atomicAdd(out, red[0] * (1.0f / (float)TWO_N));
}

extern "C" void kernel_launch(void* const* d_in, const int* in_sizes, int n_in,
                              void* d_out, int out_size, void* d_ws, size_t ws_size,
                              hipStream_t stream) {
    const float* zi = (const float*)d_in[0];
    const float* zj = (const float*)d_in[1];
    char* ws = (char*)d_ws;
    char* znB = ws;                                                    // 4 MB
    size_t off = (size_t)TWO_N * DDIM * 2;
    float* spos = (float*)(ws + off);                                  // 32 KB
    off += (size_t)TWO_N * 4;
    float* rowacc = (float*)(ws + off);                                // 32 KB
    float* out = (float*)d_out;

    ntx_norm_kernel<<<TWO_N / 4, 256, 0, stream>>>(zi, zj, znB, rowacc, out);
    ntx_gram_kernel<<<2064, 64, 0, stream>>>(znB, rowacc, spos);
    ntx_final_kernel<<<TWO_N / 256, 256, 0, stream>>>(rowacc, spos, out);
}